// Round 8
// baseline (183.821 us; speedup 1.0000x reference)
//
#include <hip/hip_runtime.h>
#include <hip/hip_bf16.h>
#include <math.h>

// CrossGeometricStructureEmbedding, round 15 (= R14 with ushort4 name
// collision fixed: HIP predefines ushort4 as HIP_vector_type -> renamed to
// ushort4v. No logic changes.)
// R13 post-mortem: 40.9us, prediction matched (conflicts = reads x 4cy law
// exact 3 rounds running; absmax pinned at bf16 noise). No pipe >40% ->
// latency/lockstep-bound: Occupancy 31.9% (~10 active waves of 16 resident),
// 8 waves per barrier group, only 2 anti-phased blocks/CU (LDS 70.6KB caps).
// R14/15 cashes in R12/R13's LDS shrinkage: P_PTS 8->4 => per-block LDS
// 50.8KB -> 3 blocks/CU, grid 1024, 24 resident waves/CU in 3 independent
// barrier groups. Per-point read/MFMA/fill/barrier counts IDENTICAL to R13 -
// pure overlap change on the verified schedule. launch_bounds(512,6) caps
// VGPR 85 (demand ~60; no manual pipelining = no spill trap). Trims:
// max3-shaped epilogue tree, setprio(1) around MFMA pair, prep rewritten
// (grid 8x64, iterative d*=10^-1/32, float4 copy).
// Predict: kernel ~31-36us, conflicts ~1.835M unchanged, WRITE_SIZE 4096,
// VGPR <= 85 (check first: >85 nullifies the occupancy gain).

typedef __attribute__((ext_vector_type(8))) short short8;
typedef __attribute__((ext_vector_type(16))) float f32x16;
typedef __attribute__((ext_vector_type(4))) unsigned int uint4v;
typedef __attribute__((ext_vector_type(4))) float float4v;
typedef __attribute__((ext_vector_type(4))) unsigned short ushort4v;

#define HH 256
#define KK 112
#define P_PTS 4
#define NPTS 4096

__device__ __forceinline__ unsigned short f2bf(float f) {
    union { float f; unsigned int u; } v; v.f = f;
    unsigned int r = v.u + 0x7fffu + ((v.u >> 16) & 1u);  // RNE
    return (unsigned short)(r >> 16);
}

__device__ __forceinline__ unsigned int pack_sc(float s, float c) {
    union { __hip_bfloat162 h; unsigned int u; } v;
    v.h = __float22bfloat162_rn(make_float2(s, c));  // low = even elem, high = odd
    return v.u;
}

// Build trimmed+augmented W: wbf[(t*256+o)*112 + e]
//   e in [0,104): W[o][e] bf16 (pairs 0..51)
//   e=104..108: u1 (x), u2 (x^2), u3 (x^3), u4 (x^4), v (1); [109,112): 0
// sin(z) ~ z - z^3/6, cos(z) ~ 1 - z^2/2 + z^4/24 for z = x*d_i, i >= 52.
__global__ __launch_bounds__(64)
void prep_w_kernel(const float* __restrict__ Wa, const float* __restrict__ Wd,
                   unsigned short* __restrict__ wbf) {
    const int r = blockIdx.x * 64 + threadIdx.x;  // 0..511
    const int t = r >> 8, o = r & 255;
    const float* W = (t == 0 ? Wd : Wa) + o * HH;
    unsigned short* dst = wbf + (t * HH + o) * KK;
    #pragma unroll
    for (int e4 = 0; e4 < 26; ++e4) {  // 104 elems as float4
        const float4v w4 = *(const float4v*)(W + e4 * 4);
        ushort4v s4;
        #pragma unroll
        for (int j = 0; j < 4; ++j) s4[j] = f2bf(w4[j]);
        *(ushort4v*)(dst + e4 * 4) = s4;
    }
    float u1 = 0.f, u2 = 0.f, u3 = 0.f, u4 = 0.f, v = 0.f;
    float d = 0.023713737056616554f;  // 10^(-52/32)
    for (int i = 52; i < 128; ++i) {
        const float d2 = d * d;
        const float ws = W[2 * i], wc = W[2 * i + 1];
        u1 += d * ws;
        u3 += -(d * d2) * (1.0f / 6.0f) * ws;
        u2 += -0.5f * d2 * wc;
        u4 += (d2 * d2) * (1.0f / 24.0f) * wc;
        v  += wc;
        d *= 0.9305720409297085f;  // 10^(-1/32)
    }
    dst[104] = f2bf(u1);
    dst[105] = f2bf(u2);
    dst[106] = f2bf(u3);
    dst[107] = f2bf(u4);
    dst[108] = f2bf(v);
    dst[109] = 0; dst[110] = 0; dst[111] = 0;
}

// E swizzle (R13-verified): row stride 256B; 16B chunk ch of row r at byte
//   r*256 + ((ch ^ (r&7)) << 4)  ==  (r<<8) ^ ((r&7)<<4) ^ (ch<<4).

__global__ __launch_bounds__(512, 6)
void cgse_main(const float* __restrict__ points,
               const float* __restrict__ anchors,
               const unsigned short* __restrict__ wbf,
               const float* __restrict__ ba,
               const float* __restrict__ bd,
               float* __restrict__ out) {
    __shared__ __align__(16) unsigned short E[2][64 * 128];  // 32 KB dbuf
    __shared__ float dms[2][P_PTS][HH];                      // 8 KB d half-maxes
    __shared__ float ams[2][P_PTS][HH];                      // 8 KB a half-maxes
    __shared__ float xs[2][P_PTS][64];                       // 2 KB
    __shared__ float anch[192];

    const int tid = threadIdx.x;
    const int wave = tid >> 6, lane = tid & 63;
    const int l5 = lane & 31, half = lane >> 5;
    const int base = blockIdx.x * P_PTS;
    const int hh = wave >> 2;            // anchor half (0: rows 0..31, 1: 32..63)
    const int colb = (wave & 3) * 64;    // wave's 64-col group

    // ---- anchors, then geometry: 4 pts x 64 anchors = 256 tasks (waves 0..3)
    if (tid < 192) anch[tid] = anchors[tid];
    __syncthreads();
    if (wave < 4) {
        const int k2 = (lane + 1) & 63;
        const int pn = base + wave;
        const float px = points[pn * 3 + 0], py = points[pn * 3 + 1], pz = points[pn * 3 + 2];
        const float r1x = px - anch[lane * 3 + 0];
        const float r1y = py - anch[lane * 3 + 1];
        const float r1z = pz - anch[lane * 3 + 2];
        const float r2x = px - anch[k2 * 3 + 0];
        const float r2y = py - anch[k2 * 3 + 1];
        const float r2z = pz - anch[k2 * 3 + 2];
        xs[0][wave][lane] = sqrtf(r1x * r1x + r1y * r1y + r1z * r1z) * 5.0f;  // /SIGMA_D
        const float cx = r1y * r2z - r1z * r2y;
        const float cy = r1z * r2x - r1x * r2z;
        const float cz = r1x * r2y - r1y * r2x;
        const float sv = sqrtf(cx * cx + cy * cy + cz * cz);
        const float cv = r1x * r2x + r1y * r2y + r1z * r2z;
        xs[1][wave][lane] = atan2f(sv, cv) * 3.8197186342054885f;  // *180/(15*pi)
    }

    // combine-phase bias (one col per thread, tid < 256)
    const float bias_c = (tid < HH) ? (ba[tid] + bd[tid]) : 0.0f;

    // fill constants: wave w fills chunk w and (w<6) chunk 8+w; chunk ch
    // covers pairs 4ch..4ch+3 (ch <= 12); ch 13 = augmented [x,x^2,x^3,x^4,1].
    const float cw = 0.15915494309189535f * __expf(-(float)wave * 0.2878231366242554f);

    // XOR-decomposed address bases (bytes)
    const int wbase = (lane << 8) ^ (((lane & 7) ^ wave) << 4);  // fill: ^ (c<<7)
    const int arow = hh * 32 + l5;                                // A-frag row (anchor)
    const int rbase = (arow << 8) ^ ((arow & 7) << 4) ^ (half << 4);  // read: ^ (ks<<5)

    // fill one 16B chunk: row = lane, chunk = wave + 8c (c compile-time).
    auto fill_chunk = [&](char* eb, int c, float x, float xc) {
        uint4v w;
        if (wave == 5 && c == 1) {            // chunk 13: [x,x^2,x^3,x^4,1,0,0,0]
            const float x2 = x * x;
            w[0] = pack_sc(x, x2);
            w[1] = pack_sc(x2 * x, x2 * x2);
            w[2] = pack_sc(1.0f, 0.0f);
            w[3] = 0u;
        } else {
            const float t0 = c ? xc * 0.1f : xc;
            const float t[4] = {t0, t0 * 0.9305720409297085f,
                                t0 * 0.8659643233600653f, t0 * 0.8058421877614819f};
            #pragma unroll
            for (int j = 0; j < 4; ++j)
                w[j] = pack_sc(__builtin_amdgcn_sinf(t[j]), __builtin_amdgcn_cosf(t[j]));
        }
        *(uint4v*)(eb + (wbase ^ (c << 7))) = w;
    };

    // ---- W strips for the wave's 2 col-tiles: 2 x 7 x short8 = 56 VGPRs
    short8 bw[2][7];
    auto loadW = [&](int t) {
        #pragma unroll
        for (int ntp = 0; ntp < 2; ++ntp) {
            const unsigned short* wr =
                wbf + (t * HH + colb + ntp * 32 + l5) * KK + half * 8;
            #pragma unroll
            for (int ks = 0; ks < 7; ++ks)
                bw[ntp][ks] = *(const short8*)(wr + ks * 16);
        }
    };

    loadW(0);
    __syncthreads();  // xs ready
    // prologue: fill buf0 for phase 0 (point 0, d-type)
    {
        const float x = xs[0][0][lane], xc = x * cw;
        fill_chunk((char*)E[0], 0, x, xc);
        if (wave < 6) fill_chunk((char*)E[0], 1, x, xc);
    }

    // phases 0..3 = d-pass (pt 0..3), 4..7 = a-pass (pt 0..3),
    // combine+output for point ph-5 at top of phases 5..8.
    #pragma unroll 1
    for (int ph = 0; ph < 9; ++ph) {
        __syncthreads();  // E[ph&1] filled; E[ph&1^1] free; partials visible

        if (ph >= 5 && tid < HH) {  // combine point q = ph-5 (both types/halves)
            const int q = ph - 5;
            out[(base + q) * HH + tid] =
                fmaxf(ams[0][q][tid], ams[1][q][tid]) +
                fmaxf(dms[0][q][tid], dms[1][q][tid]) + bias_c;
        }
        if (ph == 8) break;

        const int b = ph & 1;
        if (ph == 4) loadW(1);  // switch to Wa for the a-pass

        const bool dofill = (ph + 1) < 8;
        float xn = 0.f, xcn = 0.f;
        if (dofill) {
            const int pn = (ph + 1) & 3;
            xn = ((ph + 1) < 4 ? xs[0][pn][lane] : xs[1][pn][lane]);
            xcn = xn * cw;
        }

        const char* ebC = (const char*)E[b];
        char* ebN = (char*)E[b ^ 1];

        f32x16 acc[2];
        #pragma unroll
        for (int ntp = 0; ntp < 2; ++ntp)
            #pragma unroll
            for (int r = 0; r < 16; ++r) acc[ntp][r] = 0.f;

        #pragma unroll
        for (int ks = 0; ks < 7; ++ks) {
            if (dofill) {
                if (ks == 0) fill_chunk(ebN, 0, xn, xcn);
                if (ks == 3 && wave < 6) fill_chunk(ebN, 1, xn, xcn);
            }
            const short8 afr = *(const short8*)(ebC + (rbase ^ (ks << 5)));
            __builtin_amdgcn_s_setprio(1);
            acc[0] = __builtin_amdgcn_mfma_f32_32x32x16_bf16(afr, bw[0][ks], acc[0], 0, 0, 0);
            acc[1] = __builtin_amdgcn_mfma_f32_32x32x16_bf16(afr, bw[1][ks], acc[1], 0, 0, 0);
            __builtin_amdgcn_s_setprio(0);
        }

        // epilogue: per ntp, max over this wave's 32 anchors; max3-shaped
        // tree (fmaxf(fmaxf(a,b),c) fuses to v_max3_f32); shfl_down(32)
        // merges lane-halves. Valid on lanes 0..31 -> (hh,q) partial slot.
        const int q = ph & 3;
        float (*pm)[P_PTS][HH] = (ph < 4) ? dms : ams;
        #pragma unroll
        for (int ntp = 0; ntp < 2; ++ntp) {
            const f32x16& a = acc[ntp];
            const float v0 = fmaxf(fmaxf(a[0], a[1]), a[2]);
            const float v1 = fmaxf(fmaxf(a[3], a[4]), a[5]);
            const float v2 = fmaxf(fmaxf(a[6], a[7]), a[8]);
            const float v3 = fmaxf(fmaxf(a[9], a[10]), a[11]);
            const float v4 = fmaxf(fmaxf(a[12], a[13]), a[14]);
            const float w0 = fmaxf(fmaxf(v0, v1), v2);
            const float w1 = fmaxf(fmaxf(v3, v4), a[15]);
            float m = fmaxf(w0, w1);
            m = fmaxf(m, __shfl_down(m, 32));
            if (lane < 32) pm[hh][q][colb + ntp * 32 + l5] = m;
        }
    }
}

extern "C" void kernel_launch(void* const* d_in, const int* in_sizes, int n_in,
                              void* d_out, int out_size, void* d_ws, size_t ws_size,
                              hipStream_t stream) {
    const float* points  = (const float*)d_in[0];
    const float* anchors = (const float*)d_in[1];
    // d_in[2] = cor_score: unused by the reference
    const float* Wa = (const float*)d_in[3];
    const float* ba = (const float*)d_in[4];
    const float* Wd = (const float*)d_in[5];
    const float* bd = (const float*)d_in[6];

    unsigned short* wbf = (unsigned short*)d_ws;  // 112 KB: trimmed+aug Wd|Wa bf16

    hipLaunchKernelGGL(prep_w_kernel, dim3(8), dim3(64), 0, stream, Wa, Wd, wbf);
    hipLaunchKernelGGL(cgse_main, dim3(NPTS / P_PTS), dim3(512), 0, stream,
                       points, anchors, wbf, ba, bd, (float*)d_out);
}

// Round 9
// 100.213 us; speedup vs baseline: 1.8343x; 1.8343x over previous
//
#include <hip/hip_runtime.h>
#include <hip/hip_bf16.h>
#include <math.h>

// CrossGeometricStructureEmbedding, round 16.
// R15 post-mortem: (512,6) + R13 tiling spilled catastrophically (VGPR cap
// 85 < irreducible bw56+acc32=88; FETCH 193MB / WRITE 149MB scratch; 124us).
// The 64-col/wave tiling and 6 waves/SIMD are mutually exclusive. R16 makes
// the register math work: R12 wave-tiling (32 cols x 64 anchors, bw[7]=28)
// with the two anchor halves processed SEQUENTIALLY reusing one acc[16]:
// 28+16+dm4+temps ~= 72 <= 85. In-wave anchor merge => dms/ams LDS, partial
// stores, and the combine phase all vanish (a-pass writes out directly);
// LDS ~35KB. Cost: 14 reads/phase/wave = 2x R13 LDS traffic (~17.5us/CU
// pipe) - but R13 was idle-bound (no pipe >40%), so trading pipe-busy for
// 24 waves/CU in 3 independent barrier groups is the point. Phase loops
// fully unrolled so dm[] indexing is static (no scratch). Swizzle, fragment
// maps, fill schedule, Taylor-112 K all verbatim from verified R13.
// Predict: VGPR 72-84 + WRITE_SIZE 4096 (no-spill check FIRST), conflicts
// ~3.67M (2x, the tiling signature), occupancy ~50-60%, kernel ~28-33us.

typedef __attribute__((ext_vector_type(8))) short short8;
typedef __attribute__((ext_vector_type(16))) float f32x16;
typedef __attribute__((ext_vector_type(4))) unsigned int uint4v;
typedef __attribute__((ext_vector_type(4))) float float4v;
typedef __attribute__((ext_vector_type(4))) unsigned short ushort4v;

#define HH 256
#define KK 112
#define P_PTS 4
#define NPTS 4096

__device__ __forceinline__ unsigned short f2bf(float f) {
    union { float f; unsigned int u; } v; v.f = f;
    unsigned int r = v.u + 0x7fffu + ((v.u >> 16) & 1u);  // RNE
    return (unsigned short)(r >> 16);
}

__device__ __forceinline__ unsigned int pack_sc(float s, float c) {
    union { __hip_bfloat162 h; unsigned int u; } v;
    v.h = __float22bfloat162_rn(make_float2(s, c));  // low = even elem, high = odd
    return v.u;
}

// Build trimmed+augmented W: wbf[(t*256+o)*112 + e]
//   e in [0,104): W[o][e] bf16 (pairs 0..51)
//   e=104..108: u1 (x), u2 (x^2), u3 (x^3), u4 (x^4), v (1); [109,112): 0
// sin(z) ~ z - z^3/6, cos(z) ~ 1 - z^2/2 + z^4/24 for z = x*d_i, i >= 52.
__global__ __launch_bounds__(64)
void prep_w_kernel(const float* __restrict__ Wa, const float* __restrict__ Wd,
                   unsigned short* __restrict__ wbf) {
    const int r = blockIdx.x * 64 + threadIdx.x;  // 0..511
    const int t = r >> 8, o = r & 255;
    const float* W = (t == 0 ? Wd : Wa) + o * HH;
    unsigned short* dst = wbf + (t * HH + o) * KK;
    #pragma unroll
    for (int e4 = 0; e4 < 26; ++e4) {  // 104 elems as float4
        const float4v w4 = *(const float4v*)(W + e4 * 4);
        ushort4v s4;
        #pragma unroll
        for (int j = 0; j < 4; ++j) s4[j] = f2bf(w4[j]);
        *(ushort4v*)(dst + e4 * 4) = s4;
    }
    float u1 = 0.f, u2 = 0.f, u3 = 0.f, u4 = 0.f, v = 0.f;
    float d = 0.023713737056616554f;  // 10^(-52/32)
    for (int i = 52; i < 128; ++i) {
        const float d2 = d * d;
        const float ws = W[2 * i], wc = W[2 * i + 1];
        u1 += d * ws;
        u3 += -(d * d2) * (1.0f / 6.0f) * ws;
        u2 += -0.5f * d2 * wc;
        u4 += (d2 * d2) * (1.0f / 24.0f) * wc;
        v  += wc;
        d *= 0.9305720409297085f;  // 10^(-1/32)
    }
    dst[104] = f2bf(u1);
    dst[105] = f2bf(u2);
    dst[106] = f2bf(u3);
    dst[107] = f2bf(u4);
    dst[108] = f2bf(v);
    dst[109] = 0; dst[110] = 0; dst[111] = 0;
}

// E swizzle (R13-verified): row stride 256B; 16B chunk ch of row r at byte
//   r*256 + ((ch ^ (r&7)) << 4)  ==  (r<<8) ^ ((r&7)<<4) ^ (ch<<4).

__global__ __launch_bounds__(512, 6)
void cgse_main(const float* __restrict__ points,
               const float* __restrict__ anchors,
               const unsigned short* __restrict__ wbf,
               const float* __restrict__ ba,
               const float* __restrict__ bd,
               float* __restrict__ out) {
    __shared__ __align__(16) unsigned short E[2][64 * 128];  // 32 KB dbuf
    __shared__ float xs[2][P_PTS][64];                       // 2 KB
    __shared__ float anch[192];

    const int tid = threadIdx.x;
    const int wave = tid >> 6, lane = tid & 63;
    const int l5 = lane & 31, half = lane >> 5;
    const int base = blockIdx.x * P_PTS;
    const int col = wave * 32 + l5;  // this wave's 32-col group

    // ---- anchors, then geometry: 4 pts x 64 anchors = 256 tasks (waves 0..3)
    if (tid < 192) anch[tid] = anchors[tid];
    __syncthreads();
    if (wave < 4) {
        const int k2 = (lane + 1) & 63;
        const int pn = base + wave;
        const float px = points[pn * 3 + 0], py = points[pn * 3 + 1], pz = points[pn * 3 + 2];
        const float r1x = px - anch[lane * 3 + 0];
        const float r1y = py - anch[lane * 3 + 1];
        const float r1z = pz - anch[lane * 3 + 2];
        const float r2x = px - anch[k2 * 3 + 0];
        const float r2y = py - anch[k2 * 3 + 1];
        const float r2z = pz - anch[k2 * 3 + 2];
        xs[0][wave][lane] = sqrtf(r1x * r1x + r1y * r1y + r1z * r1z) * 5.0f;  // /SIGMA_D
        const float cx = r1y * r2z - r1z * r2y;
        const float cy = r1z * r2x - r1x * r2z;
        const float cz = r1x * r2y - r1y * r2x;
        const float sv = sqrtf(cx * cx + cy * cy + cz * cz);
        const float cv = r1x * r2x + r1y * r2y + r1z * r2z;
        xs[1][wave][lane] = atan2f(sv, cv) * 3.8197186342054885f;  // *180/(15*pi)
    }

    const float bias = ba[col] + bd[col];

    // fill constants: wave w fills chunk w and (w<6) chunk 8+w; chunk ch
    // covers pairs 4ch..4ch+3 (ch <= 12); ch 13 = augmented [x,x^2,x^3,x^4,1].
    const float cw = 0.15915494309189535f * __expf(-(float)wave * 0.2878231366242554f);

    // XOR-decomposed address bases (bytes)
    const int wbase = (lane << 8) ^ (((lane & 7) ^ wave) << 4);  // fill: ^ (c<<7)
    // read: A-frag row = hh*32 + l5; (32+l5)&7 == l5&7, so hh=1 is +8192 B.
    const int rbase = (l5 << 8) ^ ((l5 & 7) << 4) ^ (half << 4); // ^ (ks<<5), +hh*8192

    // fill one 16B chunk: row = lane, chunk = wave + 8c (c compile-time).
    auto fill_chunk = [&](char* eb, int c, float x, float xc) {
        uint4v w;
        if (wave == 5 && c == 1) {            // chunk 13: [x,x^2,x^3,x^4,1,0,0,0]
            const float x2 = x * x;
            w[0] = pack_sc(x, x2);
            w[1] = pack_sc(x2 * x, x2 * x2);
            w[2] = pack_sc(1.0f, 0.0f);
            w[3] = 0u;
        } else {
            const float t0 = c ? xc * 0.1f : xc;
            const float t[4] = {t0, t0 * 0.9305720409297085f,
                                t0 * 0.8659643233600653f, t0 * 0.8058421877614819f};
            #pragma unroll
            for (int j = 0; j < 4; ++j)
                w[j] = pack_sc(__builtin_amdgcn_sinf(t[j]), __builtin_amdgcn_cosf(t[j]));
        }
        *(uint4v*)(eb + (wbase ^ (c << 7))) = w;
    };

    // ---- W strip for the wave's 32 cols: 7 x short8 = 28 VGPRs
    short8 bw[7];
    auto loadW = [&](int t) {
        const unsigned short* wr = wbf + (t * HH + col) * KK + half * 8;
        #pragma unroll
        for (int ks = 0; ks < 7; ++ks)
            bw[ks] = *(const short8*)(wr + ks * 16);
    };

    // max over one anchor-half: 16 acc regs -> scalar (max3-shaped tree)
    auto htree = [&](const f32x16& a) -> float {
        const float v0 = fmaxf(fmaxf(a[0], a[1]), a[2]);
        const float v1 = fmaxf(fmaxf(a[3], a[4]), a[5]);
        const float v2 = fmaxf(fmaxf(a[6], a[7]), a[8]);
        const float v3 = fmaxf(fmaxf(a[9], a[10]), a[11]);
        const float v4 = fmaxf(fmaxf(a[12], a[13]), a[14]);
        const float w0 = fmaxf(fmaxf(v0, v1), v2);
        const float w1 = fmaxf(fmaxf(v3, v4), a[15]);
        return fmaxf(w0, w1);
    };

    loadW(0);
    __syncthreads();  // xs ready
    // prologue: fill buf0 for phase 0 (point 0, d-type)
    {
        const float x = xs[0][0][lane], xc = x * cw;
        fill_chunk((char*)E[0], 0, x, xc);
        if (wave < 6) fill_chunk((char*)E[0], 1, x, xc);
    }

    float dm[P_PTS];  // d-pass maxes (statically indexed; loops fully unrolled)

    // ---- d-pass: phases 0..3 (pt = q)
    #pragma unroll
    for (int q = 0; q < 4; ++q) {
        __syncthreads();  // E[q&1] filled; E[q&1^1] free
        const char* ebC = (const char*)E[q & 1];
        char* ebN = (char*)E[(q & 1) ^ 1];
        // next phase: d-type pt q+1, except q=3 -> a-type pt 0
        const float xn = (q < 3) ? xs[0][q + 1][lane] : xs[1][0][lane];
        const float xcn = xn * cw;

        float mh[2];
        #pragma unroll
        for (int hh = 0; hh < 2; ++hh) {
            if (hh == 0) fill_chunk(ebN, 0, xn, xcn);
            else if (wave < 6) fill_chunk(ebN, 1, xn, xcn);
            f32x16 acc;
            #pragma unroll
            for (int r = 0; r < 16; ++r) acc[r] = 0.f;
            #pragma unroll
            for (int ks = 0; ks < 7; ++ks) {
                const short8 afr = *(const short8*)
                    (ebC + ((rbase ^ (ks << 5)) + hh * 8192));
                __builtin_amdgcn_s_setprio(1);
                acc = __builtin_amdgcn_mfma_f32_32x32x16_bf16(afr, bw[ks], acc, 0, 0, 0);
                __builtin_amdgcn_s_setprio(0);
            }
            mh[hh] = htree(acc);
        }
        float m = fmaxf(mh[0], mh[1]);
        m = fmaxf(m, __shfl_down(m, 32));
        dm[q] = m;  // valid on lanes 0..31
    }

    loadW(1);  // Wa; loads retire at the next barrier (one-time L2 hit)

    // ---- a-pass: phases 4..7 (pt = q), writes out directly
    #pragma unroll
    for (int q = 0; q < 4; ++q) {
        __syncthreads();
        const char* ebC = (const char*)E[q & 1];
        char* ebN = (char*)E[(q & 1) ^ 1];
        const bool dofill = q < 3;
        const float xn = dofill ? xs[1][q + 1][lane] : 0.f;
        const float xcn = xn * cw;

        float mh[2];
        #pragma unroll
        for (int hh = 0; hh < 2; ++hh) {
            if (dofill) {
                if (hh == 0) fill_chunk(ebN, 0, xn, xcn);
                else if (wave < 6) fill_chunk(ebN, 1, xn, xcn);
            }
            f32x16 acc;
            #pragma unroll
            for (int r = 0; r < 16; ++r) acc[r] = 0.f;
            #pragma unroll
            for (int ks = 0; ks < 7; ++ks) {
                const short8 afr = *(const short8*)
                    (ebC + ((rbase ^ (ks << 5)) + hh * 8192));
                __builtin_amdgcn_s_setprio(1);
                acc = __builtin_amdgcn_mfma_f32_32x32x16_bf16(afr, bw[ks], acc, 0, 0, 0);
                __builtin_amdgcn_s_setprio(0);
            }
            mh[hh] = htree(acc);
        }
        float m = fmaxf(mh[0], mh[1]);
        m = fmaxf(m, __shfl_down(m, 32));
        if (lane < 32)
            out[(base + q) * HH + col] = m + dm[q] + bias;
    }
}

extern "C" void kernel_launch(void* const* d_in, const int* in_sizes, int n_in,
                              void* d_out, int out_size, void* d_ws, size_t ws_size,
                              hipStream_t stream) {
    const float* points  = (const float*)d_in[0];
    const float* anchors = (const float*)d_in[1];
    // d_in[2] = cor_score: unused by the reference
    const float* Wa = (const float*)d_in[3];
    const float* ba = (const float*)d_in[4];
    const float* Wd = (const float*)d_in[5];
    const float* bd = (const float*)d_in[6];

    unsigned short* wbf = (unsigned short*)d_ws;  // 112 KB: trimmed+aug Wd|Wa bf16

    hipLaunchKernelGGL(prep_w_kernel, dim3(8), dim3(64), 0, stream, Wa, Wd, wbf);
    hipLaunchKernelGGL(cgse_main, dim3(NPTS / P_PTS), dim3(512), 0, stream,
                       points, anchors, wbf, ba, bd, (float*)d_out);
}